// Round 7
// baseline (108.102 us; speedup 1.0000x reference)
//
#include <hip/hip_runtime.h>

#define NG 512
#define NPX 262144
#define GRID1D 32
#define NCELL 1024                 // 32x32 cells
#define NSEG 32                    // cursor segments (atomic contention / 32)
#define SEGCAP 32                  // mean 8 per (seg,cell); Poisson tail safe
#define PXCAP 384                  // mean 256 per cell; ~8 sigma headroom
#define KSCALE 0.72134752044448170368f   /* 0.5 * log2(e) */
#define WCULL 30.0f                /* keep if u^2+v^2 <= l2a + 30 (term >= 2^-30) */

// d_ws layout (bytes):
//   cur:     [0, NSEG*NCELL*4)              = 128 KB   (memset 0 each call)
//   entries: [+128K, NSEG*NCELL*SEGCAP*16)  = 16.78 MB (x, y, idx_bits, 0)
//   pg:      [next, NG*32)                  = 16 KB    two float4/gaussian
//   cg:      [next, NG*16)                  = 8 KB     (mx, my, hx, hy)

// ---------------- pass 0: per-Gaussian parameter precompute ----------------
__global__ __launch_bounds__(256)
void prep_kernel(const float* __restrict__ alphas,
                 const float* __restrict__ means,
                 const float* __restrict__ rotations,
                 const float* __restrict__ scales,
                 float4* __restrict__ pg, float4* __restrict__ cg)
{
    int n = blockIdx.x * 256 + threadIdx.x;
    if (n >= NG) return;
    float rot = rotations[n];
    float sth, cth;
    sincosf(rot, &sth, &cth);
    float s0 = scales[2 * n + 0];
    float s1 = scales[2 * n + 1];
    // RS = [[s0*c, -s1*s], [s0*s, s1*c]], RSSR = RS*RS^T, cov = inv(RSSR)
    float r00 = s0 * cth, r01 = -s1 * sth;
    float r10 = s0 * sth, r11 =  s1 * cth;
    float Ar = r00 * r00 + r01 * r01;
    float Br = r00 * r10 + r01 * r11;
    float Dr = r10 * r10 + r11 * r11;
    float det = Ar * Dr - Br * Br;
    float kc00 =  KSCALE * Dr / det;
    float kc01 = -KSCALE * Br / det;
    // Cholesky of KSCALE*cov: k*q = (p00*dx + p01*dy)^2 + (p11*dy)^2
    float p00 = sqrtf(kc00);
    float p01 = kc01 / p00;
    float p11 = sqrtf(KSCALE / Dr);   // exact: kc11 - kc01^2/kc00 = KSCALE/Dr
    float mx = means[2 * n + 0];
    float my = means[2 * n + 1];
    float nu  = -(p00 * mx + p01 * my);
    float nv  = -(p11 * my);
    float l2a = log2f(alphas[n]);     // alpha==0 -> -inf -> culled, correct

    pg[2 * n + 0] = make_float4(p00, p01, nu, l2a);
    pg[2 * n + 1] = make_float4(p11, nv, 0.0f, 0.0f);

    // bbox half-widths of the {u^2+v^2 <= l2a+WCULL} ellipse in x-space:
    // M = P^T P = KSCALE*cov, M^-1 = RSSR/KSCALE -> hx = r*sqrt(Ar/k), hy = r*sqrt(Dr/k)
    float r2 = l2a + WCULL;
    float hx = -1.0f, hy = -1.0f;
    if (r2 > 0.0f) {
        float rk = r2 * (1.0f / KSCALE);
        hx = sqrtf(rk * Ar);
        hy = sqrtf(rk * Dr);
    }
    cg[n] = make_float4(mx, my, hx, hy);
}

// ---------------- pass 1: segmented spatial binning ----------------
__global__ __launch_bounds__(256)
void bin_kernel(const float* __restrict__ x, int* __restrict__ cur,
                float4* __restrict__ entries)
{
    int t = blockIdx.x * 256 + threadIdx.x;       // 0..131071, 2 pixels each
    float4 p2 = ((const float4*)x)[t];
    int seg = blockIdx.x & (NSEG - 1);

    int cxa = min((int)(p2.x * GRID1D), GRID1D - 1);
    int cya = min((int)(p2.y * GRID1D), GRID1D - 1);
    int ca  = cya * GRID1D + cxa;
    int cxb = min((int)(p2.z * GRID1D), GRID1D - 1);
    int cyb = min((int)(p2.w * GRID1D), GRID1D - 1);
    int cb  = cyb * GRID1D + cxb;

    int pa = atomicAdd(&cur[seg * NCELL + ca], 1);
    int pb = atomicAdd(&cur[seg * NCELL + cb], 1);
    if (pa < SEGCAP)
        entries[(seg * NCELL + ca) * SEGCAP + pa] =
            make_float4(p2.x, p2.y, __int_as_float(2 * t), 0.0f);
    if (pb < SEGCAP)
        entries[(seg * NCELL + cb) * SEGCAP + pb] =
            make_float4(p2.z, p2.w, __int_as_float(2 * t + 1), 0.0f);
}

// ---------------- pass 2: per-cell cull + splat ----------------
__global__ __launch_bounds__(128, 2)
void splat_kernel(const int* __restrict__ cur,
                  const float4* __restrict__ entries,
                  const float4* __restrict__ pg,
                  const float4* __restrict__ cg,
                  float* __restrict__ out)
{
    __shared__ float4 gl[2 * (NG + 4)];
    __shared__ float2 px[PXCAP];
    __shared__ int    pidx[PXCAP];
    __shared__ int    cnt[NSEG], preS[NSEG];
    __shared__ int    nkept, totsh;

    int tid  = threadIdx.x;
    int cell = blockIdx.x;

    if (tid == 0) nkept = 0;
    if (tid < NSEG) cnt[tid] = min(cur[tid * NCELL + cell], SEGCAP);
    __syncthreads();

    // exclusive prefix over 32 segment counts on wave 0 (shfl scan, no LDS RMW)
    if (tid < 64) {
        int v = (tid < NSEG) ? cnt[tid] : 0;
        #pragma unroll
        for (int d = 1; d < NSEG; d <<= 1) {
            int w = __shfl_up(v, d, 64);
            if (tid >= d) v += w;
        }
        if (tid < NSEG) preS[tid] = v - cnt[tid];
        if (tid == NSEG - 1) totsh = min(v, PXCAP);
    }
    __syncthreads();
    int total = totsh;

    // stage this cell's pixels into a dense LDS list (pow-2 slot decode)
    #pragma unroll
    for (int slot = 0; slot < NSEG * SEGCAP; slot += 128) {
        int sl = slot + tid;
        int s = sl >> 5;            // / SEGCAP
        int k = sl & (SEGCAP - 1);
        if (k < cnt[s]) {
            int dst = preS[s] + k;
            if (dst < PXCAP) {
                float4 e = entries[(s * NCELL + cell) * SEGCAP + k];
                px[dst]   = make_float2(e.x, e.y);
                pidx[dst] = __float_as_int(e.z);
            }
        }
    }

    // cull via box-overlap against precomputed ellipse bboxes (cg is L2-hot)
    float ccx = ((cell & (GRID1D - 1)) + 0.5f) * (1.0f / GRID1D);
    float ccy = ((cell >> 5)           + 0.5f) * (1.0f / GRID1D);
    const float HW = 0.5f / GRID1D;
    for (int n = tid; n < NG; n += 128) {
        float4 c = cg[n];
        if (fabsf(c.x - ccx) <= c.z + HW && fabsf(c.y - ccy) <= c.w + HW) {
            int slot = atomicAdd(&nkept, 1);
            gl[2 * slot + 0] = pg[2 * n + 0];
            gl[2 * slot + 1] = pg[2 * n + 1];
        }
    }
    __syncthreads();

    int nk = nkept;
    int nround = (nk + 3) & ~3;           // pad to multiple of 4
    if (tid < nround - nk) {
        gl[2 * (nk + tid) + 0] = make_float4(0.0f, 0.0f, 0.0f, -10000.0f);
        gl[2 * (nk + tid) + 1] = make_float4(0.0f, 0.0f, 0.0f, 0.0f);
    }
    __syncthreads();

    // 2 pixels per thread; term = 2^(l2a - u^2 - v^2)
    for (int p0 = tid; 2 * p0 < total; p0 += 128) {
        int ia = 2 * p0, ib = ia + 1;
        bool hasB = ib < total;
        float2 A = px[ia];
        float2 B = hasB ? px[ib] : A;
        float a0 = 0.0f, a1 = 0.0f, b0 = 0.0f, b1 = 0.0f;

        for (int j = 0; j < nround; j += 4) {
            #pragma unroll
            for (int jj = 0; jj < 4; ++jj) {
                float4 P = gl[2 * (j + jj) + 0];   // broadcast ds_read_b128
                float4 Q = gl[2 * (j + jj) + 1];
                float uA = fmaf(P.x, A.x, fmaf(P.y, A.y, P.z));
                float vA = fmaf(Q.x, A.y, Q.y);
                float wA = fmaf(-vA, vA, fmaf(-uA, uA, P.w));
                float uB = fmaf(P.x, B.x, fmaf(P.y, B.y, P.z));
                float vB = fmaf(Q.x, B.y, Q.y);
                float wB = fmaf(-vB, vB, fmaf(-uB, uB, P.w));
                float eA = __builtin_amdgcn_exp2f(wA);
                float eB = __builtin_amdgcn_exp2f(wB);
                if (jj & 1) { a1 += eA; b1 += eB; }
                else        { a0 += eA; b0 += eB; }
            }
        }

        out[pidx[ia]] = a0 + a1;
        if (hasB) out[pidx[ib]] = b0 + b1;
    }
}

extern "C" void kernel_launch(void* const* d_in, const int* in_sizes, int n_in,
                              void* d_out, int out_size, void* d_ws, size_t ws_size,
                              hipStream_t stream) {
    const float* x         = (const float*)d_in[0];
    const float* alphas    = (const float*)d_in[1];
    const float* means     = (const float*)d_in[2];
    const float* rotations = (const float*)d_in[3];
    const float* scales    = (const float*)d_in[4];
    float* out = (float*)d_out;

    char* ws = (char*)d_ws;
    size_t off = 0;
    int*    cur     = (int*)(ws + off);    off += (size_t)NSEG * NCELL * sizeof(int);
    float4* entries = (float4*)(ws + off); off += (size_t)NSEG * NCELL * SEGCAP * sizeof(float4);
    float4* pg      = (float4*)(ws + off); off += (size_t)NG * 2 * sizeof(float4);
    float4* cg      = (float4*)(ws + off);

    hipMemsetAsync(cur, 0, NSEG * NCELL * sizeof(int), stream);
    prep_kernel<<<(NG + 255) / 256, 256, 0, stream>>>(alphas, means, rotations, scales, pg, cg);
    bin_kernel<<<NPX / 512, 256, 0, stream>>>(x, cur, entries);
    splat_kernel<<<NCELL, 128, 0, stream>>>(cur, entries, pg, cg, out);
}